// Round 10
// baseline (48.573 us; speedup 1.0000x reference)
//
#include <hip/hip_runtime.h>
#include <math.h>

constexpr int Bn = 2048;
constexpr int Nn = 4096;
constexpr int TPB = 256;   // 4 waves

typedef float floatx4 __attribute__((ext_vector_type(4)));

struct G {
    floatx4 w4, k0, k1, k2, p0, p1, p2;
};

__device__ __forceinline__ floatx4 ntload(const float* p) {
    return __builtin_nontemporal_load(reinterpret_cast<const floatx4*>(p));
}

__device__ __forceinline__ G loadg(const float* __restrict__ wb,
                                   const float* __restrict__ kpb,
                                   const float* __restrict__ psb,
                                   int idx)
{
    G g;
    g.w4 = ntload(wb + idx);
    g.k0 = ntload(kpb + idx);
    g.k1 = ntload(kpb + Nn + idx);
    g.k2 = ntload(kpb + 2 * Nn + idx);
    g.p0 = ntload(psb + idx);
    g.p1 = ntload(psb + Nn + idx);
    g.p2 = ntload(psb + 2 * Nn + idx);
    return g;
}

// One block per batch. Non-temporal streaming (bypass L3 retention),
// depth-2 software pipeline, wave reduce, then thread 0 solves the 3x3
// Kabsch in fp32 (5 Jacobi sweeps) and writes R,t directly -- no second
// kernel, no ws round-trip.
__global__ __launch_bounds__(TPB, 4)
void kabsch_fused(const float* __restrict__ kp,
                  const float* __restrict__ ps,
                  const float* __restrict__ wt,
                  float* __restrict__ out)
{
    const int b   = blockIdx.x;
    const int tid = threadIdx.x;
    const float* kpb = kp + (size_t)b * 3 * Nn;
    const float* psb = ps + (size_t)b * 3 * Nn;
    const float* wb  = wt + (size_t)b * Nn;

    const int i0 = tid * 4;

    float acc[16];
#pragma unroll
    for (int i = 0; i < 16; ++i) acc[i] = 0.f;

#define ACCUM(GG, C) do {                                               \
        const float wj = GG.w4.C;                                       \
        const float a0 = GG.k0.C, a1 = GG.k1.C, a2 = GG.k2.C;           \
        const float q0 = GG.p0.C, q1 = GG.p1.C, q2 = GG.p2.C;           \
        const float wa0 = wj * a0, wa1 = wj * a1, wa2 = wj * a2;        \
        acc[0]  += wj;                                                  \
        acc[1]  += wa0;      acc[2]  += wa1;      acc[3]  += wa2;       \
        acc[4]  += wj * q0;  acc[5]  += wj * q1;  acc[6]  += wj * q2;   \
        acc[7]  += wa0 * q0; acc[8]  += wa0 * q1; acc[9]  += wa0 * q2;  \
        acc[10] += wa1 * q0; acc[11] += wa1 * q1; acc[12] += wa1 * q2;  \
        acc[13] += wa2 * q0; acc[14] += wa2 * q1; acc[15] += wa2 * q2;  \
    } while (0)
#define CONSUME(GG) ACCUM(GG, x); ACCUM(GG, y); ACCUM(GG, z); ACCUM(GG, w)

    G g0 = loadg(wb, kpb, psb, i0);
    G g1 = loadg(wb, kpb, psb, i0 + 1024);
    CONSUME(g0);
    G g2 = loadg(wb, kpb, psb, i0 + 2048);
    CONSUME(g1);
    G g3 = loadg(wb, kpb, psb, i0 + 3072);
    CONSUME(g2);
    CONSUME(g3);
#undef CONSUME
#undef ACCUM

    // wave butterfly reduction of 16 accumulators
#pragma unroll
    for (int i = 0; i < 16; ++i) {
        float v = acc[i];
#pragma unroll
        for (int off = 32; off > 0; off >>= 1) v += __shfl_down(v, off);
        acc[i] = v;
    }

    __shared__ float red[4][16];
    const int lane = tid & 63;
    const int wid  = tid >> 6;
    if (lane == 0) {
#pragma unroll
        for (int i = 0; i < 16; ++i) red[wid][i] = acc[i];
    }
    __syncthreads();
    if (tid != 0) return;

    // ---- fused epilogue: 3x3 Kabsch in fp32, thread 0 ----
    float s[16];
#pragma unroll
    for (int i = 0; i < 16; ++i)
        s[i] = red[0][i] + red[1][i] + red[2][i] + red[3][i];

    const float W    = s[0];
    const float invW = 1.0f / W;
    float kc[3] = { s[1] * invW, s[2] * invW, s[3] * invW };
    float pc[3] = { s[4] * invW, s[5] * invW, s[6] * invW };
    float H[3][3];
#pragma unroll
    for (int i = 0; i < 3; ++i)
#pragma unroll
        for (int j = 0; j < 3; ++j)
            H[i][j] = s[7 + i * 3 + j] * invW - kc[i] * pc[j];

    // A = H^T H (symmetric)
    float A[3][3];
#pragma unroll
    for (int i = 0; i < 3; ++i)
#pragma unroll
        for (int j = 0; j < 3; ++j)
            A[i][j] = H[0][i] * H[0][j] + H[1][i] * H[1][j] + H[2][i] * H[2][j];

    float V[3][3] = { {1,0,0}, {0,1,0}, {0,0,1} };

#define JROT(P,Q) do {                                                       \
        const float apq = A[P][Q];                                           \
        if (fabsf(apq) > 1e-30f) {                                           \
            const float th = (A[Q][Q] - A[P][P]) / (2.0f * apq);             \
            const float tt = copysignf(1.0f, th) / (fabsf(th) + sqrtf(1.0f + th * th)); \
            const float cc = rsqrtf(1.0f + tt * tt);                         \
            const float sn = tt * cc;                                        \
            _Pragma("unroll")                                                \
            for (int k = 0; k < 3; ++k) {                                    \
                const float akp = A[k][P], akq = A[k][Q];                    \
                A[k][P] = cc * akp - sn * akq;                               \
                A[k][Q] = sn * akp + cc * akq;                               \
            }                                                                \
            _Pragma("unroll")                                                \
            for (int k = 0; k < 3; ++k) {                                    \
                const float apk = A[P][k], aqk = A[Q][k];                    \
                A[P][k] = cc * apk - sn * aqk;                               \
                A[Q][k] = sn * apk + cc * aqk;                               \
            }                                                                \
            _Pragma("unroll")                                                \
            for (int k = 0; k < 3; ++k) {                                    \
                const float vkp = V[k][P], vkq = V[k][Q];                    \
                V[k][P] = cc * vkp - sn * vkq;                               \
                V[k][Q] = sn * vkp + cc * vkq;                               \
            }                                                                \
        }                                                                    \
    } while (0)

    for (int sweep = 0; sweep < 5; ++sweep) { JROT(0,1); JROT(0,2); JROT(1,2); }
#undef JROT

    float lam[3] = { A[0][0], A[1][1], A[2][2] };
#define CSWAP(I,J) if (lam[I] < lam[J]) {                                    \
        const float tl = lam[I]; lam[I] = lam[J]; lam[J] = tl;               \
        _Pragma("unroll")                                                    \
        for (int k = 0; k < 3; ++k) {                                        \
            const float tv = V[k][I]; V[k][I] = V[k][J]; V[k][J] = tv; }     \
    }
    CSWAP(0, 1); CSWAP(0, 2); CSWAP(1, 2);
#undef CSWAP

    float v0[3] = { V[0][0], V[1][0], V[2][0] };
    float v1[3] = { V[0][1], V[1][1], V[2][1] };
    float v2[3] = { v0[1] * v1[2] - v0[2] * v1[1],
                    v0[2] * v1[0] - v0[0] * v1[2],
                    v0[0] * v1[1] - v0[1] * v1[0] };

    float u0[3], u1[3];
#pragma unroll
    for (int i = 0; i < 3; ++i)
        u0[i] = H[i][0] * v0[0] + H[i][1] * v0[1] + H[i][2] * v0[2];
    {
        float n0 = sqrtf(u0[0]*u0[0] + u0[1]*u0[1] + u0[2]*u0[2]);
        n0 = fmaxf(n0, 1e-30f);
#pragma unroll
        for (int i = 0; i < 3; ++i) u0[i] /= n0;
    }
    {
        float b1[3];
#pragma unroll
        for (int i = 0; i < 3; ++i)
            b1[i] = H[i][0] * v1[0] + H[i][1] * v1[1] + H[i][2] * v1[2];
        const float dp = u0[0]*b1[0] + u0[1]*b1[1] + u0[2]*b1[2];
#pragma unroll
        for (int i = 0; i < 3; ++i) b1[i] -= dp * u0[i];
        float n1 = sqrtf(b1[0]*b1[0] + b1[1]*b1[1] + b1[2]*b1[2]);
        if (n1 > 1e-18f) {
#pragma unroll
            for (int i = 0; i < 3; ++i) u1[i] = b1[i] / n1;
        } else {
            float e[3] = { 0, 0, 0 };
            if (fabsf(u0[0]) <= fabsf(u0[1]) && fabsf(u0[0]) <= fabsf(u0[2])) e[0] = 1;
            else if (fabsf(u0[1]) <= fabsf(u0[2])) e[1] = 1;
            else e[2] = 1;
            float c1[3] = { u0[1]*e[2] - u0[2]*e[1],
                            u0[2]*e[0] - u0[0]*e[2],
                            u0[0]*e[1] - u0[1]*e[0] };
            float nc = sqrtf(c1[0]*c1[0] + c1[1]*c1[1] + c1[2]*c1[2]);
            nc = fmaxf(nc, 1e-30f);
#pragma unroll
            for (int i = 0; i < 3; ++i) u1[i] = c1[i] / nc;
        }
    }

    const float detH =
        H[0][0] * (H[1][1] * H[2][2] - H[1][2] * H[2][1]) -
        H[0][1] * (H[1][0] * H[2][2] - H[1][2] * H[2][0]) +
        H[0][2] * (H[1][0] * H[2][1] - H[1][1] * H[2][0]);
    const float d = (detH < 0.0f) ? -1.0f : 1.0f;

    float u2[3] = { d * (u0[1]*u1[2] - u0[2]*u1[1]),
                    d * (u0[2]*u1[0] - u0[0]*u1[2]),
                    d * (u0[0]*u1[1] - u0[1]*u1[0]) };

    float R[3][3];
#pragma unroll
    for (int i = 0; i < 3; ++i)
#pragma unroll
        for (int j = 0; j < 3; ++j)
            R[i][j] = v0[i] * u0[j] + v1[i] * u1[j] + d * v2[i] * u2[j];

    float t[3];
#pragma unroll
    for (int i = 0; i < 3; ++i)
        t[i] = pc[i] - (R[i][0] * kc[0] + R[i][1] * kc[1] + R[i][2] * kc[2]);

    float* outR = out + (size_t)b * 9;
    float* outT = out + (size_t)Bn * 9 + (size_t)b * 3;
#pragma unroll
    for (int i = 0; i < 3; ++i)
#pragma unroll
        for (int j = 0; j < 3; ++j)
            outR[i * 3 + j] = R[i][j];
#pragma unroll
    for (int i = 0; i < 3; ++i) outT[i] = t[i];
}

extern "C" void kernel_launch(void* const* d_in, const int* in_sizes, int n_in,
                              void* d_out, int out_size, void* d_ws, size_t ws_size,
                              hipStream_t stream) {
    const float* kp = (const float*)d_in[0];
    const float* ps = (const float*)d_in[1];
    const float* wt = (const float*)d_in[2];
    float* out = (float*)d_out;
    kabsch_fused<<<Bn, TPB, 0, stream>>>(kp, ps, wt, out);
}

// Round 11
// 45.218 us; speedup vs baseline: 1.0742x; 1.0742x over previous
//
#include <hip/hip_runtime.h>
#include <math.h>

constexpr int Bn = 2048;
constexpr int Nn = 4096;
constexpr int TPB = 256;   // 4 waves

typedef float floatx4 __attribute__((ext_vector_type(4)));

struct G {
    floatx4 w4, k0, k1, k2, p0, p1, p2;
};

__device__ __forceinline__ floatx4 ntload(const float* p) {
    return __builtin_nontemporal_load(reinterpret_cast<const floatx4*>(p));
}

__device__ __forceinline__ G loadg(const float* __restrict__ wb,
                                   const float* __restrict__ kpb,
                                   const float* __restrict__ psb,
                                   int idx)
{
    G g;
    g.w4 = ntload(wb + idx);
    g.k0 = ntload(kpb + idx);
    g.k1 = ntload(kpb + Nn + idx);
    g.k2 = ntload(kpb + 2 * Nn + idx);
    g.p0 = ntload(psb + idx);
    g.p1 = ntload(psb + Nn + idx);
    g.p2 = ntload(psb + 2 * Nn + idx);
    return g;
}

// ---------------- Kernel A: streaming partial sums ----------------
// One block per batch; depth-2 software pipeline of 4 float4 groups.
// ALL input loads are non-temporal (nt): bypass L3 retention so the
// 229 MB input streams from HBM instead of thrashing the 256 MB L3.
__global__ __launch_bounds__(TPB, 4)
void kabsch_stream(const float* __restrict__ kp,
                   const float* __restrict__ ps,
                   const float* __restrict__ wt,
                   float* __restrict__ ws)
{
    const int b   = blockIdx.x;
    const int tid = threadIdx.x;
    const float* kpb = kp + (size_t)b * 3 * Nn;
    const float* psb = ps + (size_t)b * 3 * Nn;
    const float* wb  = wt + (size_t)b * Nn;

    const int i0 = tid * 4;

    float acc[16];
#pragma unroll
    for (int i = 0; i < 16; ++i) acc[i] = 0.f;

#define ACCUM(GG, C) do {                                               \
        const float wj = GG.w4.C;                                       \
        const float a0 = GG.k0.C, a1 = GG.k1.C, a2 = GG.k2.C;           \
        const float q0 = GG.p0.C, q1 = GG.p1.C, q2 = GG.p2.C;           \
        const float wa0 = wj * a0, wa1 = wj * a1, wa2 = wj * a2;        \
        acc[0]  += wj;                                                  \
        acc[1]  += wa0;      acc[2]  += wa1;      acc[3]  += wa2;       \
        acc[4]  += wj * q0;  acc[5]  += wj * q1;  acc[6]  += wj * q2;   \
        acc[7]  += wa0 * q0; acc[8]  += wa0 * q1; acc[9]  += wa0 * q2;  \
        acc[10] += wa1 * q0; acc[11] += wa1 * q1; acc[12] += wa1 * q2;  \
        acc[13] += wa2 * q0; acc[14] += wa2 * q1; acc[15] += wa2 * q2;  \
    } while (0)
#define CONSUME(GG) ACCUM(GG, x); ACCUM(GG, y); ACCUM(GG, z); ACCUM(GG, w)

    G g0 = loadg(wb, kpb, psb, i0);
    G g1 = loadg(wb, kpb, psb, i0 + 1024);
    CONSUME(g0);
    G g2 = loadg(wb, kpb, psb, i0 + 2048);
    CONSUME(g1);
    G g3 = loadg(wb, kpb, psb, i0 + 3072);
    CONSUME(g2);
    CONSUME(g3);
#undef CONSUME
#undef ACCUM

    // wave butterfly reduction of 16 accumulators
#pragma unroll
    for (int i = 0; i < 16; ++i) {
        float v = acc[i];
#pragma unroll
        for (int off = 32; off > 0; off >>= 1) v += __shfl_down(v, off);
        acc[i] = v;
    }

    __shared__ float red[4][16];
    const int lane = tid & 63;
    const int wid  = tid >> 6;
    if (lane == 0) {
#pragma unroll
        for (int i = 0; i < 16; ++i) red[wid][i] = acc[i];
    }
    __syncthreads();
    if (tid < 16) {
        const float v = red[0][tid] + red[1][tid] + red[2][tid] + red[3][tid];
        ws[(size_t)b * 16 + tid] = v;
    }
}

// ---------------- Kernel B: parallel 3x3 Kabsch epilogue (fp32) ----------------
// one THREAD per batch; fp32 Jacobi (5 sweeps) -- ~4x lower latency than fp64,
// accuracy floor is set by the fp32 streaming accumulation anyway.
__global__ void kabsch_epilogue(const float* __restrict__ ws,
                                float* __restrict__ out)
{
    const int b = blockIdx.x * blockDim.x + threadIdx.x;
    if (b >= Bn) return;

    const float* p = ws + (size_t)b * 16;
    float s[16];
#pragma unroll
    for (int i = 0; i < 16; ++i) s[i] = p[i];

    const float W    = s[0];
    const float invW = 1.0f / W;
    float kc[3] = { s[1] * invW, s[2] * invW, s[3] * invW };
    float pc[3] = { s[4] * invW, s[5] * invW, s[6] * invW };
    float H[3][3];
#pragma unroll
    for (int i = 0; i < 3; ++i)
#pragma unroll
        for (int j = 0; j < 3; ++j)
            H[i][j] = s[7 + i * 3 + j] * invW - kc[i] * pc[j];

    // A = H^T H (symmetric)
    float A[3][3];
#pragma unroll
    for (int i = 0; i < 3; ++i)
#pragma unroll
        for (int j = 0; j < 3; ++j)
            A[i][j] = H[0][i] * H[0][j] + H[1][i] * H[1][j] + H[2][i] * H[2][j];

    float V[3][3] = { {1,0,0}, {0,1,0}, {0,0,1} };

#define JROT(P,Q) do {                                                       \
        const float apq = A[P][Q];                                           \
        if (fabsf(apq) > 1e-30f) {                                           \
            const float th = (A[Q][Q] - A[P][P]) / (2.0f * apq);             \
            const float tt = copysignf(1.0f, th) / (fabsf(th) + sqrtf(1.0f + th * th)); \
            const float cc = rsqrtf(1.0f + tt * tt);                         \
            const float sn = tt * cc;                                        \
            _Pragma("unroll")                                                \
            for (int k = 0; k < 3; ++k) {                                    \
                const float akp = A[k][P], akq = A[k][Q];                    \
                A[k][P] = cc * akp - sn * akq;                               \
                A[k][Q] = sn * akp + cc * akq;                               \
            }                                                                \
            _Pragma("unroll")                                                \
            for (int k = 0; k < 3; ++k) {                                    \
                const float apk = A[P][k], aqk = A[Q][k];                    \
                A[P][k] = cc * apk - sn * aqk;                               \
                A[Q][k] = sn * apk + cc * aqk;                               \
            }                                                                \
            _Pragma("unroll")                                                \
            for (int k = 0; k < 3; ++k) {                                    \
                const float vkp = V[k][P], vkq = V[k][Q];                    \
                V[k][P] = cc * vkp - sn * vkq;                               \
                V[k][Q] = sn * vkp + cc * vkq;                               \
            }                                                                \
        }                                                                    \
    } while (0)

    for (int sweep = 0; sweep < 5; ++sweep) { JROT(0,1); JROT(0,2); JROT(1,2); }
#undef JROT

    float lam[3] = { A[0][0], A[1][1], A[2][2] };
#define CSWAP(I,J) if (lam[I] < lam[J]) {                                    \
        const float tl = lam[I]; lam[I] = lam[J]; lam[J] = tl;               \
        _Pragma("unroll")                                                    \
        for (int k = 0; k < 3; ++k) {                                        \
            const float tv = V[k][I]; V[k][I] = V[k][J]; V[k][J] = tv; }     \
    }
    CSWAP(0, 1); CSWAP(0, 2); CSWAP(1, 2);
#undef CSWAP

    float v0[3] = { V[0][0], V[1][0], V[2][0] };
    float v1[3] = { V[0][1], V[1][1], V[2][1] };
    float v2[3] = { v0[1] * v1[2] - v0[2] * v1[1],
                    v0[2] * v1[0] - v0[0] * v1[2],
                    v0[0] * v1[1] - v0[1] * v1[0] };

    float u0[3], u1[3];
#pragma unroll
    for (int i = 0; i < 3; ++i)
        u0[i] = H[i][0] * v0[0] + H[i][1] * v0[1] + H[i][2] * v0[2];
    {
        float n0 = sqrtf(u0[0]*u0[0] + u0[1]*u0[1] + u0[2]*u0[2]);
        n0 = fmaxf(n0, 1e-30f);
#pragma unroll
        for (int i = 0; i < 3; ++i) u0[i] /= n0;
    }
    {
        float b1[3];
#pragma unroll
        for (int i = 0; i < 3; ++i)
            b1[i] = H[i][0] * v1[0] + H[i][1] * v1[1] + H[i][2] * v1[2];
        const float dp = u0[0]*b1[0] + u0[1]*b1[1] + u0[2]*b1[2];
#pragma unroll
        for (int i = 0; i < 3; ++i) b1[i] -= dp * u0[i];
        float n1 = sqrtf(b1[0]*b1[0] + b1[1]*b1[1] + b1[2]*b1[2]);
        if (n1 > 1e-18f) {
#pragma unroll
            for (int i = 0; i < 3; ++i) u1[i] = b1[i] / n1;
        } else {
            float e[3] = { 0, 0, 0 };
            if (fabsf(u0[0]) <= fabsf(u0[1]) && fabsf(u0[0]) <= fabsf(u0[2])) e[0] = 1;
            else if (fabsf(u0[1]) <= fabsf(u0[2])) e[1] = 1;
            else e[2] = 1;
            float c1[3] = { u0[1]*e[2] - u0[2]*e[1],
                            u0[2]*e[0] - u0[0]*e[2],
                            u0[0]*e[1] - u0[1]*e[0] };
            float nc = sqrtf(c1[0]*c1[0] + c1[1]*c1[1] + c1[2]*c1[2]);
            nc = fmaxf(nc, 1e-30f);
#pragma unroll
            for (int i = 0; i < 3; ++i) u1[i] = c1[i] / nc;
        }
    }

    const float detH =
        H[0][0] * (H[1][1] * H[2][2] - H[1][2] * H[2][1]) -
        H[0][1] * (H[1][0] * H[2][2] - H[1][2] * H[2][0]) +
        H[0][2] * (H[1][0] * H[2][1] - H[1][1] * H[2][0]);
    const float d = (detH < 0.0f) ? -1.0f : 1.0f;

    float u2[3] = { d * (u0[1]*u1[2] - u0[2]*u1[1]),
                    d * (u0[2]*u1[0] - u0[0]*u1[2]),
                    d * (u0[0]*u1[1] - u0[1]*u1[0]) };

    float R[3][3];
#pragma unroll
    for (int i = 0; i < 3; ++i)
#pragma unroll
        for (int j = 0; j < 3; ++j)
            R[i][j] = v0[i] * u0[j] + v1[i] * u1[j] + d * v2[i] * u2[j];

    float t[3];
#pragma unroll
    for (int i = 0; i < 3; ++i)
        t[i] = pc[i] - (R[i][0] * kc[0] + R[i][1] * kc[1] + R[i][2] * kc[2]);

    float* outR = out + (size_t)b * 9;
    float* outT = out + (size_t)Bn * 9 + (size_t)b * 3;
#pragma unroll
    for (int i = 0; i < 3; ++i)
#pragma unroll
        for (int j = 0; j < 3; ++j)
            outR[i * 3 + j] = R[i][j];
#pragma unroll
    for (int i = 0; i < 3; ++i) outT[i] = t[i];
}

extern "C" void kernel_launch(void* const* d_in, const int* in_sizes, int n_in,
                              void* d_out, int out_size, void* d_ws, size_t ws_size,
                              hipStream_t stream) {
    const float* kp = (const float*)d_in[0];
    const float* ps = (const float*)d_in[1];
    const float* wt = (const float*)d_in[2];
    float* out = (float*)d_out;
    float* ws  = (float*)d_ws;
    kabsch_stream<<<Bn, TPB, 0, stream>>>(kp, ps, wt, ws);
    kabsch_epilogue<<<(Bn + 255) / 256, 256, 0, stream>>>(ws, out);
}